// Round 10
// baseline (194.497 us; speedup 1.0000x reference)
//
#include <hip/hip_runtime.h>

constexpr int DIMN = 160;
constexpr int VOL  = DIMN * DIMN * DIMN;   // 4,096,000
constexpr int BATCH = 2;
constexpr long long NPTS = (long long)BATCH * VOL;  // 8,192,000

__device__ __forceinline__ int iclampi(int v, int lo, int hi) {
    return v < lo ? lo : (v > hi ? hi : v);
}

// ---------------------------------------------------------------------------
// Kernel A: gather 5x5x5 conv, replicate pad. EXACT r6 math (8-wide x-strip,
// 2 z-planes, V[12] edge selects, j<5 / j>=1 accumulator guards) with ONE
// change: per j-plane, all 5 rows' loads (15 x float4) are issued as a batch
// BEFORE the FMA block -> ~15 outstanding loads/wave instead of ~3.
// r5-r9 showed dur pinned at 52-78us across load-count/occupancy variants
// (VALUBusy 37-41%, HBM <=22%) = per-wave latency serialization.
// ---------------------------------------------------------------------------
__global__ __launch_bounds__(256, 3) void conv3d_p(
    const float* __restrict__ x, const float* __restrict__ w,
    float* __restrict__ y)
{
    __shared__ float wl[125];
    if (threadIdx.x < 125) wl[threadIdx.x] = w[threadIdx.x];
    __syncthreads();

    const int sid = blockIdx.x * 256 + threadIdx.x;   // < 512,000
    const int xs  = sid % 20;            // x-strip
    int r = sid / 20;
    const int yy0 = r % DIMN;            // H row
    r /= DIMN;
    const int zp = r % 80;               // z-pair
    const int b  = r / 80;

    const int x0 = xs * 8;
    const int z0 = zp * 2;
    const float* xb = x + (size_t)b * VOL;

    const bool eL = (xs == 0), eR = (xs == 19);
    const int xa = eL ? 0 : (x0 - 2);
    const int xc = eR ? (DIMN - 4) : (x0 + 6);

    float acc0[8], acc1[8];
#pragma unroll
    for (int t = 0; t < 8; ++t) { acc0[t] = 0.f; acc1[t] = 0.f; }

#pragma unroll
    for (int j = 0; j < 6; ++j) {
        const int zz = iclampi(z0 - 2 + j, 0, DIMN - 1);
        const float* pl = xb + (size_t)zz * DIMN * DIMN;

        // ---- load phase: 15 float4 issued back-to-back ----
        float4 A[5], Bv[5], C[5];
#pragma unroll
        for (int ky = 0; ky < 5; ++ky) {
            const int yy = iclampi(yy0 - 2 + ky, 0, DIMN - 1);
            const float* row = pl + (size_t)yy * DIMN;
            A[ky]  = *(const float4*)(row + xa);
            Bv[ky] = *(const float4*)(row + x0 + 2);
            C[ky]  = *(const float4*)(row + xc);
        }

        // ---- compute phase (verified r5/r6 V[12] + guards) ----
#pragma unroll
        for (int ky = 0; ky < 5; ++ky) {
            float V[12];
            V[0]  = A[ky].x;
            V[1]  = eL ? A[ky].x : A[ky].y;
            V[2]  = eL ? A[ky].x : A[ky].z;
            V[3]  = eL ? A[ky].y : A[ky].w;
            V[4]  = Bv[ky].x; V[5] = Bv[ky].y; V[6] = Bv[ky].z; V[7] = Bv[ky].w;
            V[8]  = eR ? C[ky].z : C[ky].x;
            V[9]  = eR ? C[ky].w : C[ky].y;
            V[10] = eR ? C[ky].w : C[ky].z;
            V[11] = C[ky].w;
#pragma unroll
            for (int kx = 0; kx < 5; ++kx) {
                if (j < 5) {   // output z0: kz = j
                    const float wa = wl[(j * 5 + ky) * 5 + kx];
#pragma unroll
                    for (int t = 0; t < 8; ++t)
                        acc0[t] = fmaf(wa, V[kx + t], acc0[t]);
                }
                if (j >= 1) {  // output z0+1: kz = j-1
                    const float wb = wl[((j - 1) * 5 + ky) * 5 + kx];
#pragma unroll
                    for (int t = 0; t < 8; ++t)
                        acc1[t] = fmaf(wb, V[kx + t], acc1[t]);
                }
            }
        }
    }

    float* yr0 = y + (((size_t)b * DIMN + z0)     * DIMN + yy0) * DIMN + x0;
    float* yr1 = y + (((size_t)b * DIMN + z0 + 1) * DIMN + yy0) * DIMN + x0;
    *(float4*)(yr0)     = make_float4(acc0[0], acc0[1], acc0[2], acc0[3]);
    *(float4*)(yr0 + 4) = make_float4(acc0[4], acc0[5], acc0[6], acc0[7]);
    *(float4*)(yr1)     = make_float4(acc1[0], acc1[1], acc1[2], acc1[3]);
    *(float4*)(yr1 + 4) = make_float4(acc1[4], acc1[5], acc1[6], acc1[7]);
}

// ---------------------------------------------------------------------------
// Kernel B: Hessian (jnp.gradient twice) + MLP, strip-8. VERBATIM r9
// (passed, absmax 0.0039).
// ---------------------------------------------------------------------------
__global__ __launch_bounds__(256) void hess_mlp8(
    const float* __restrict__ Yg,
    const float* __restrict__ w1, const float* __restrict__ b1,
    const float* __restrict__ w2, const float* __restrict__ b2,
    float* __restrict__ out)
{
    __shared__ float wlds[81];  // w1[0..59], b1[60..69], w2[70..79], b2[80]
    {
        const int tid = threadIdx.x;
        if (tid < 60) wlds[tid] = w1[tid];
        if (tid >= 60 && tid < 70) wlds[tid] = b1[tid - 60];
        if (tid >= 70 && tid < 80) wlds[tid] = w2[tid - 70];
        if (tid == 80) wlds[80] = b2[0];
    }
    __syncthreads();

    const int sid = blockIdx.x * 256 + threadIdx.x;   // < 1,024,000
    const int xs  = sid % 20;
    int r = sid / 20;
    const int y = r % DIMN;
    r /= DIMN;
    const int z = r % DIMN;
    const int b = r / DIMN;

    const int x0 = xs * 8;
    const float* Yb = Yg + (size_t)b * VOL;

    const int zp1 = min(z + 1, DIMN - 1), zm1 = max(z - 1, 0);
    const int zp2 = min(z + 2, DIMN - 1), zm2 = max(z - 2, 0);
    const int yp1 = min(y + 1, DIMN - 1), ym1 = max(y - 1, 0);
    const int yp2 = min(y + 2, DIMN - 1), ym2 = max(y - 2, 0);

    auto rowp = [&](int zz, int yy) { return Yb + ((size_t)zz * DIMN + yy) * DIMN; };

    const bool eL = (xs == 0), eR = (xs == 19);
    const int xa = eL ? 0 : (x0 - 2);
    const int xc = eR ? (DIMN - 4) : (x0 + 6);

    auto loadW = [&](const float* row, float* W) {
        const float4 A = *(const float4*)(row + xa);
        const float4 B = *(const float4*)(row + x0 + 2);
        const float4 C = *(const float4*)(row + xc);
        W[0]  = A.x;
        W[1]  = eL ? A.x : A.y;
        W[2]  = eL ? A.x : A.z;
        W[3]  = eL ? A.y : A.w;
        W[4]  = B.x; W[5] = B.y; W[6] = B.z; W[7] = B.w;
        W[8]  = eR ? C.z : C.x;
        W[9]  = eR ? C.w : C.y;
        W[10] = eR ? C.w : C.z;
        W[11] = C.w;
    };
    auto loadU = [&](const float* row, float* U) {
        const float4 u0 = *(const float4*)(row + x0);
        const float4 u1 = *(const float4*)(row + x0 + 4);
        U[0] = u0.x; U[1] = u0.y; U[2] = u0.z; U[3] = u0.w;
        U[4] = u1.x; U[5] = u1.y; U[6] = u1.z; U[7] = u1.w;
    };

    float Wc[12], Wzp[12], Wzm[12], Wyp[12], Wym[12];
    loadW(rowp(z, y),   Wc);
    loadW(rowp(zp1, y), Wzp);
    loadW(rowp(zm1, y), Wzm);
    loadW(rowp(z, yp1), Wyp);
    loadW(rowp(z, ym1), Wym);

    const float sz1 = (z > 0 && z < DIMN - 1) ? 0.5f : 1.0f;
    const float szp = (z < DIMN - 2) ? 0.5f : 1.0f;
    const float szm = (z > 1) ? 0.5f : 1.0f;
    const float sy1 = (y > 0 && y < DIMN - 1) ? 0.5f : 1.0f;
    const float syp = (y < DIMN - 2) ? 0.5f : 1.0f;
    const float sym = (y > 1) ? 0.5f : 1.0f;
    const bool zTop = (z == DIMN - 1), zBot = (z == 0);
    const bool yTop = (y == DIMN - 1), yBot = (y == 0);

    float H0[8], H1[8], H2[8], H3[8], H4[8], H5[8];
    {   // d2/dz2 -- consume z+-2 rows eagerly
        float U1[8], U2[8];
        loadU(rowp(zp2, y), U1);
        loadU(rowp(zm2, y), U2);
#pragma unroll
        for (int t = 0; t < 8; ++t) {
            const float B0 = zTop ? Wzm[t + 2] : Wc[t + 2];
            const float C0 = zBot ? Wzp[t + 2] : Wc[t + 2];
            H0[t] = sz1 * (szp * (U1[t] - B0) - szm * (C0 - U2[t]));
        }
    }
    {   // d2/dy2
        float U1[8], U2[8];
        loadU(rowp(z, yp2), U1);
        loadU(rowp(z, ym2), U2);
#pragma unroll
        for (int t = 0; t < 8; ++t) {
            const float B3 = yTop ? Wym[t + 2] : Wc[t + 2];
            const float C3 = yBot ? Wyp[t + 2] : Wc[t + 2];
            H3[t] = sy1 * (syp * (U1[t] - B3) - sym * (C3 - U2[t]));
        }
    }
    {   // dz dy -- four diagonal rows
        float Upp[8], Upm[8], Ump[8], Umm[8];
        loadU(rowp(zp1, yp1), Upp);
        loadU(rowp(zp1, ym1), Upm);
        loadU(rowp(zm1, yp1), Ump);
        loadU(rowp(zm1, ym1), Umm);
#pragma unroll
        for (int t = 0; t < 8; ++t)
            H1[t] = sy1 * sz1 * ((Upp[t] - Ump[t]) - (Upm[t] - Umm[t]));
    }
#pragma unroll
    for (int t = 0; t < 8; ++t) {
        const int xx = x0 + t;
        const float sx1 = (xx > 0 && xx < DIMN - 1) ? 0.5f : 1.0f;
        const float sxp = (xx < DIMN - 2) ? 0.5f : 1.0f;
        const float sxm = (xx > 1) ? 0.5f : 1.0f;
        H2[t] = sx1 * sz1 * ((Wzp[t + 3] - Wzm[t + 3]) - (Wzp[t + 1] - Wzm[t + 1]));
        H4[t] = sx1 * sy1 * ((Wyp[t + 3] - Wym[t + 3]) - (Wyp[t + 1] - Wym[t + 1]));
        const float aP = (xx == DIMN - 1) ? Wc[t + 1] : Wc[t + 2];
        const float cM = (xx == 0)        ? Wc[t + 3] : Wc[t + 2];
        H5[t] = sx1 * (sxp * (Wc[t + 4] - aP) - sxm * (cM - Wc[t]));
    }

    // MLP: oo-outer, LDS-broadcast weights reused across the 8-strip
    float o[8];
    {
        const float bb2 = wlds[80];
#pragma unroll
        for (int t = 0; t < 8; ++t) o[t] = bb2;
    }
#pragma unroll
    for (int oo = 0; oo < 10; ++oo) {
        const float wr0 = wlds[oo * 6 + 0];
        const float wr1 = wlds[oo * 6 + 1];
        const float wr2 = wlds[oo * 6 + 2];
        const float wr3 = wlds[oo * 6 + 3];
        const float wr4 = wlds[oo * 6 + 4];
        const float wr5 = wlds[oo * 6 + 5];
        const float bb  = wlds[60 + oo];
        const float w2v = wlds[70 + oo];
#pragma unroll
        for (int t = 0; t < 8; ++t) {
            float a = bb;
            a = fmaf(H0[t], wr0, a);
            a = fmaf(H1[t], wr1, a);
            a = fmaf(H2[t], wr2, a);
            a = fmaf(H3[t], wr3, a);
            a = fmaf(H4[t], wr4, a);
            a = fmaf(H5[t], wr5, a);
            a = fmaxf(a, 0.f);
            o[t] = fmaf(a, w2v, o[t]);
        }
    }

    float res[8];
#pragma unroll
    for (int t = 0; t < 8; ++t) res[t] = 1.0f / (1.0f + __expf(-o[t]));
    float* op = out + (size_t)sid * 8;
    *(float4*)(op)     = make_float4(res[0], res[1], res[2], res[3]);
    *(float4*)(op + 4) = make_float4(res[4], res[5], res[6], res[7]);
}

// ---------------------------------------------------------------------------
extern "C" void kernel_launch(void* const* d_in, const int* in_sizes, int n_in,
                              void* d_out, int out_size, void* d_ws, size_t ws_size,
                              hipStream_t stream)
{
    const float* x  = (const float*)d_in[0];
    const float* cw = (const float*)d_in[1];
    const float* w1 = (const float*)d_in[2];
    const float* b1 = (const float*)d_in[3];
    const float* w2 = (const float*)d_in[4];
    const float* b2 = (const float*)d_in[5];
    float* outp = (float*)d_out;
    float* yws  = (float*)d_ws;

    const int nblkA = (int)(NPTS / 16 / 256);  // 2000 blocks (16 outputs/thread)
    conv3d_p<<<nblkA, 256, 0, stream>>>(x, cw, yws);

    const int nblkB = (int)(NPTS / 8 / 256);   // 4000 blocks (8 outputs/thread)
    hess_mlp8<<<nblkB, 256, 0, stream>>>(yws, w1, b1, w2, b2, outp);
}

// Round 11
// 163.060 us; speedup vs baseline: 1.1928x; 1.1928x over previous
//
#include <hip/hip_runtime.h>

constexpr int DIMN = 160;
constexpr int VOL  = DIMN * DIMN * DIMN;   // 4,096,000
constexpr int BATCH = 2;
constexpr long long NPTS = (long long)BATCH * VOL;  // 8,192,000

__device__ __forceinline__ int iclampi(int v, int lo, int hi) {
    return v < lo ? lo : (v > hi ? hi : v);
}

// ---------------------------------------------------------------------------
// Kernel A: gather-formulation 5x5x5 conv, replicate pad. VERBATIM r6 math
// (best measured conv: 52us). ONE addition: XCD-aware bijective block
// swizzle (T1) so neighbor blocks (sharing halo rows) land on the same
// XCD's L2. Grid 2000 = 8 x 250 exactly.
// ---------------------------------------------------------------------------
__global__ __launch_bounds__(256) void conv3d_g2(
    const float* __restrict__ x, const float* __restrict__ w,
    float* __restrict__ y)
{
    __shared__ float wl[125];
    if (threadIdx.x < 125) wl[threadIdx.x] = w[threadIdx.x];
    __syncthreads();

    // XCD swizzle: XCD k (blocks k, k+8, ...) -> contiguous sid chunk
    const int obid = blockIdx.x;                 // 0..1999
    const int sb   = (obid & 7) * 250 + (obid >> 3);
    const int sid  = sb * 256 + threadIdx.x;

    const int xs  = sid % 20;            // x-strip
    int r = sid / 20;
    const int yy0 = r % DIMN;            // H row
    r /= DIMN;
    const int zp = r % 80;               // z-pair
    const int b  = r / 80;

    const int x0 = xs * 8;
    const int z0 = zp * 2;
    const float* xb = x + (size_t)b * VOL;

    const bool eL = (xs == 0), eR = (xs == 19);
    const int xa = eL ? 0 : (x0 - 2);
    const int xc = eR ? (DIMN - 4) : (x0 + 6);

    float acc0[8], acc1[8];
#pragma unroll
    for (int t = 0; t < 8; ++t) { acc0[t] = 0.f; acc1[t] = 0.f; }

#pragma unroll
    for (int j = 0; j < 6; ++j) {
        const int zz = iclampi(z0 - 2 + j, 0, DIMN - 1);
#pragma unroll
        for (int ky = 0; ky < 5; ++ky) {
            const int yy = iclampi(yy0 - 2 + ky, 0, DIMN - 1);
            const float* row = xb + ((size_t)zz * DIMN + yy) * DIMN;
            const float4 A = *(const float4*)(row + xa);
            const float4 B = *(const float4*)(row + x0 + 2);
            const float4 C = *(const float4*)(row + xc);
            // V[i] <-> x index clamp(x0-2+i), i = 0..11  (verified r5/r6)
            float V[12];
            V[0]  = A.x;
            V[1]  = eL ? A.x : A.y;
            V[2]  = eL ? A.x : A.z;
            V[3]  = eL ? A.y : A.w;
            V[4]  = B.x; V[5] = B.y; V[6] = B.z; V[7] = B.w;
            V[8]  = eR ? C.z : C.x;
            V[9]  = eR ? C.w : C.y;
            V[10] = eR ? C.w : C.z;
            V[11] = C.w;
#pragma unroll
            for (int kx = 0; kx < 5; ++kx) {
                if (j < 5) {   // output z0: kz = j
                    const float wa = wl[(j * 5 + ky) * 5 + kx];
#pragma unroll
                    for (int t = 0; t < 8; ++t)
                        acc0[t] = fmaf(wa, V[kx + t], acc0[t]);
                }
                if (j >= 1) {  // output z0+1: kz = j-1
                    const float wb = wl[((j - 1) * 5 + ky) * 5 + kx];
#pragma unroll
                    for (int t = 0; t < 8; ++t)
                        acc1[t] = fmaf(wb, V[kx + t], acc1[t]);
                }
            }
        }
    }

    float* yr0 = y + (((size_t)b * DIMN + z0)     * DIMN + yy0) * DIMN + x0;
    float* yr1 = y + (((size_t)b * DIMN + z0 + 1) * DIMN + yy0) * DIMN + x0;
    *(float4*)(yr0)     = make_float4(acc0[0], acc0[1], acc0[2], acc0[3]);
    *(float4*)(yr0 + 4) = make_float4(acc0[4], acc0[5], acc0[6], acc0[7]);
    *(float4*)(yr1)     = make_float4(acc1[0], acc1[1], acc1[2], acc1[3]);
    *(float4*)(yr1 + 4) = make_float4(acc1[4], acc1[5], acc1[6], acc1[7]);
}

// ---------------------------------------------------------------------------
// Kernel B: Hessian (jnp.gradient twice) + MLP, strip-4. VERBATIM r6 code
// (best measured pairing; <=51us). ONE addition: XCD swizzle, 8000 = 8x1000.
// ---------------------------------------------------------------------------
__global__ __launch_bounds__(256) void hess_mlp4(
    const float* __restrict__ Yg,
    const float* __restrict__ w1, const float* __restrict__ b1,
    const float* __restrict__ w2, const float* __restrict__ b2,
    float* __restrict__ out)
{
    __shared__ float wlds[81];  // w1[0..59], b1[60..69], w2[70..79], b2[80]
    {
        const int tid = threadIdx.x;
        if (tid < 60) wlds[tid] = w1[tid];
        if (tid >= 60 && tid < 70) wlds[tid] = b1[tid - 60];
        if (tid >= 70 && tid < 80) wlds[tid] = w2[tid - 70];
        if (tid == 80) wlds[80] = b2[0];
    }
    __syncthreads();

    const int obid = blockIdx.x;                 // 0..7999
    const int sb   = (obid & 7) * 1000 + (obid >> 3);
    const int sid  = sb * 256 + threadIdx.x;     // strip id, < 2,048,000

    const int rrow = sid / 40;                   // row over (b,z,y)
    const int x0 = (sid - rrow * 40) * 4;
    const int b = rrow / (DIMN * DIMN);
    int rem = rrow - b * (DIMN * DIMN);
    const int z = rem / DIMN;
    const int y = rem - z * DIMN;

    const float* Yb = Yg + (size_t)b * VOL;
    const int zp1 = min(z + 1, DIMN - 1), zm1 = max(z - 1, 0);
    const int zp2 = min(z + 2, DIMN - 1), zm2 = max(z - 2, 0);
    const int yp1 = min(y + 1, DIMN - 1), ym1 = max(y - 1, 0);
    const int yp2 = min(y + 2, DIMN - 1), ym2 = max(y - 2, 0);

    auto rowp = [&](int zz, int yy) { return Yb + ((size_t)zz * DIMN + yy) * DIMN; };

    const int xl = max(x0 - 2, 0);
    const int xr = (x0 < DIMN - 4) ? (x0 + 4) : (DIMN - 2);
    const bool xL = (x0 > 0), xR = (x0 < DIMN - 4);

    const float* Rc = rowp(z, y);
    float4 Cc = *(const float4*)(Rc + x0);
    float2 Cl = *(const float2*)(Rc + xl);
    float2 Cr = *(const float2*)(Rc + xr);
    const float* Rzp = rowp(zp1, y);
    float4 Pzc = *(const float4*)(Rzp + x0);
    float2 Pzl = *(const float2*)(Rzp + xl);
    float2 Pzr = *(const float2*)(Rzp + xr);
    const float* Rzm = rowp(zm1, y);
    float4 Mzc = *(const float4*)(Rzm + x0);
    float2 Mzl = *(const float2*)(Rzm + xl);
    float2 Mzr = *(const float2*)(Rzm + xr);
    const float* Ryp = rowp(z, yp1);
    float4 Pyc = *(const float4*)(Ryp + x0);
    float2 Pyl = *(const float2*)(Ryp + xl);
    float2 Pyr = *(const float2*)(Ryp + xr);
    const float* Rym = rowp(z, ym1);
    float4 Myc = *(const float4*)(Rym + x0);
    float2 Myl = *(const float2*)(Rym + xl);
    float2 Myr = *(const float2*)(Rym + xr);
    float4 Z2p = *(const float4*)(rowp(zp2, y) + x0);
    float4 Z2m = *(const float4*)(rowp(zm2, y) + x0);
    float4 Y2p = *(const float4*)(rowp(z, yp2) + x0);
    float4 Y2m = *(const float4*)(rowp(z, ym2) + x0);
    float4 Dpp = *(const float4*)(rowp(zp1, yp1) + x0);
    float4 Dpm = *(const float4*)(rowp(zp1, ym1) + x0);
    float4 Dmp = *(const float4*)(rowp(zm1, yp1) + x0);
    float4 Dmm = *(const float4*)(rowp(zm1, ym1) + x0);

    float V[8];
    V[0] = Cl.x;
    V[1] = xL ? Cl.y : Cl.x;
    V[2] = Cc.x; V[3] = Cc.y; V[4] = Cc.z; V[5] = Cc.w;
    V[6] = xR ? Cr.x : Cr.y;
    V[7] = Cr.y;
    float PZ[6], MZ[6], PY[6], MY[6];
    PZ[0] = xL ? Pzl.y : Pzl.x; PZ[1] = Pzc.x; PZ[2] = Pzc.y; PZ[3] = Pzc.z; PZ[4] = Pzc.w; PZ[5] = xR ? Pzr.x : Pzr.y;
    MZ[0] = xL ? Mzl.y : Mzl.x; MZ[1] = Mzc.x; MZ[2] = Mzc.y; MZ[3] = Mzc.z; MZ[4] = Mzc.w; MZ[5] = xR ? Mzr.x : Mzr.y;
    PY[0] = xL ? Pyl.y : Pyl.x; PY[1] = Pyc.x; PY[2] = Pyc.y; PY[3] = Pyc.z; PY[4] = Pyc.w; PY[5] = xR ? Pyr.x : Pyr.y;
    MY[0] = xL ? Myl.y : Myl.x; MY[1] = Myc.x; MY[2] = Myc.y; MY[3] = Myc.z; MY[4] = Myc.w; MY[5] = xR ? Myr.x : Myr.y;
    float C4[4]  = {Cc.x, Cc.y, Cc.z, Cc.w};
    float Z2P[4] = {Z2p.x, Z2p.y, Z2p.z, Z2p.w};
    float Z2M[4] = {Z2m.x, Z2m.y, Z2m.z, Z2m.w};
    float Y2P[4] = {Y2p.x, Y2p.y, Y2p.z, Y2p.w};
    float Y2M[4] = {Y2m.x, Y2m.y, Y2m.z, Y2m.w};
    float DPP[4] = {Dpp.x, Dpp.y, Dpp.z, Dpp.w};
    float DPM[4] = {Dpm.x, Dpm.y, Dpm.z, Dpm.w};
    float DMP[4] = {Dmp.x, Dmp.y, Dmp.z, Dmp.w};
    float DMM[4] = {Dmm.x, Dmm.y, Dmm.z, Dmm.w};

    const float sz1 = (z > 0 && z < DIMN - 1) ? 0.5f : 1.0f;
    const float szp = (z < DIMN - 2) ? 0.5f : 1.0f;
    const float szm = (z > 1) ? 0.5f : 1.0f;
    const float sy1 = (y > 0 && y < DIMN - 1) ? 0.5f : 1.0f;
    const float syp = (y < DIMN - 2) ? 0.5f : 1.0f;
    const float sym = (y > 1) ? 0.5f : 1.0f;
    const bool zTop = (z == DIMN - 1), zBot = (z == 0);
    const bool yTop = (y == DIMN - 1), yBot = (y == 0);

    float H0[4], H1[4], H2[4], H3[4], H4[4], H5[4];
#pragma unroll
    for (int t = 0; t < 4; ++t) {
        const int xx = x0 + t;
        const float sx1 = (xx > 0 && xx < DIMN - 1) ? 0.5f : 1.0f;
        const float sxp = (xx < DIMN - 2) ? 0.5f : 1.0f;
        const float sxm = (xx > 1) ? 0.5f : 1.0f;

        {
            const float B0 = zTop ? MZ[t + 1] : C4[t];
            const float C0 = zBot ? PZ[t + 1] : C4[t];
            H0[t] = sz1 * (szp * (Z2P[t] - B0) - szm * (C0 - Z2M[t]));
        }
        H1[t] = sy1 * sz1 * ((DPP[t] - DMP[t]) - (DPM[t] - DMM[t]));
        H2[t] = sx1 * sz1 * ((PZ[t + 2] - MZ[t + 2]) - (PZ[t] - MZ[t]));
        {
            const float B3 = yTop ? MY[t + 1] : C4[t];
            const float C3 = yBot ? PY[t + 1] : C4[t];
            H3[t] = sy1 * (syp * (Y2P[t] - B3) - sym * (C3 - Y2M[t]));
        }
        H4[t] = sx1 * sy1 * ((PY[t + 2] - MY[t + 2]) - (PY[t] - MY[t]));
        {
            const float aP = (xx == DIMN - 1) ? V[t + 1] : V[t + 2];
            const float cM = (xx == 0) ? V[t + 3] : V[t + 2];
            H5[t] = sx1 * (sxp * (V[t + 4] - aP) - sxm * (cM - V[t]));
        }
    }

    float o[4];
    {
        const float bb2 = wlds[80];
#pragma unroll
        for (int t = 0; t < 4; ++t) o[t] = bb2;
    }
#pragma unroll
    for (int oo = 0; oo < 10; ++oo) {
        const float wr0 = wlds[oo * 6 + 0];
        const float wr1 = wlds[oo * 6 + 1];
        const float wr2 = wlds[oo * 6 + 2];
        const float wr3 = wlds[oo * 6 + 3];
        const float wr4 = wlds[oo * 6 + 4];
        const float wr5 = wlds[oo * 6 + 5];
        const float bb  = wlds[60 + oo];
        const float w2v = wlds[70 + oo];
#pragma unroll
        for (int t = 0; t < 4; ++t) {
            float a = bb;
            a = fmaf(H0[t], wr0, a);
            a = fmaf(H1[t], wr1, a);
            a = fmaf(H2[t], wr2, a);
            a = fmaf(H3[t], wr3, a);
            a = fmaf(H4[t], wr4, a);
            a = fmaf(H5[t], wr5, a);
            a = fmaxf(a, 0.f);
            o[t] = fmaf(a, w2v, o[t]);
        }
    }

    float res[4];
#pragma unroll
    for (int t = 0; t < 4; ++t) res[t] = 1.0f / (1.0f + __expf(-o[t]));
    *(float4*)(out + (size_t)sid * 4) =
        make_float4(res[0], res[1], res[2], res[3]);
}

// ---------------------------------------------------------------------------
extern "C" void kernel_launch(void* const* d_in, const int* in_sizes, int n_in,
                              void* d_out, int out_size, void* d_ws, size_t ws_size,
                              hipStream_t stream)
{
    const float* x  = (const float*)d_in[0];
    const float* cw = (const float*)d_in[1];
    const float* w1 = (const float*)d_in[2];
    const float* b1 = (const float*)d_in[3];
    const float* w2 = (const float*)d_in[4];
    const float* b2 = (const float*)d_in[5];
    float* outp = (float*)d_out;
    float* yws  = (float*)d_ws;

    const int nblkA = (int)(NPTS / 16 / 256);  // 2000 blocks (16 outputs/thread)
    conv3d_g2<<<nblkA, 256, 0, stream>>>(x, cw, yws);

    const int nblkB = (int)(NPTS / 4 / 256);   // 8000 blocks (4 outputs/thread)
    hess_mlp4<<<nblkB, 256, 0, stream>>>(yws, w1, b1, w2, b2, outp);
}